// Round 7
// baseline (469.840 us; speedup 1.0000x reference)
//
#include <hip/hip_runtime.h>

// ---------------- types / helpers ----------------
typedef __bf16 bf16;
typedef __attribute__((ext_vector_type(8)))  bf16     bf16x8;
typedef __attribute__((ext_vector_type(4)))  bf16     bf16x4;
typedef __attribute__((ext_vector_type(16))) float    f32x16;
typedef __attribute__((ext_vector_type(4)))  float    f32x4;
typedef __attribute__((ext_vector_type(4)))  unsigned uint4v;
typedef __attribute__((ext_vector_type(2)))  unsigned uint2v;

#define SLEN 4096
#define HDIM 64
#define EMB 512
#define SCALE_LOG2E 0.1803336100254854f  /* 0.125 * log2(e), folded into Q at projection */

__device__ __forceinline__ f32x16 mfma32(bf16x8 a, bf16x8 b, f32x16 c) {
  return __builtin_amdgcn_mfma_f32_32x32x16_bf16(a, b, c, 0, 0, 0);
}

// async global->LDS, 16B per lane (used by out_proj only now)
__device__ __forceinline__ void cp16(const void* g, const void* l) {
  __builtin_amdgcn_global_load_lds(
      (__attribute__((address_space(1))) unsigned int*)(unsigned long long)g,
      (__attribute__((address_space(3))) unsigned int*)(unsigned int)(unsigned long long)l,
      16, 0, 0);
}

__device__ __forceinline__ unsigned pk2(float a, float b) {
  unsigned short ua = __builtin_bit_cast(unsigned short, (bf16)a);
  unsigned short ub = __builtin_bit_cast(unsigned short, (bf16)b);
  return (unsigned)ua | ((unsigned)ub << 16);
}

// ---------------- kernel 1: QKV projections (MFMA), Q pre-scaled ----------------
// Outputs: Qb [bh][s][64] bf16 (pre-scaled by 0.125*log2e)
//          KVimg [bh][half(2)][tile32(64)][ K: 4 frags | V: 4 frags ][lane 64][8 bf16]
//            K frag c, lane = kv_local + 32*lh, elem j = K[kv][d=16c+8lh+j]
//            V frag f = db*2+cc, lane = d_local + 32*lh, elem j = V[kv=16cc+8lh+j][d=db*32+d_local]
__global__ __launch_bounds__(256, 2) void proj_qkv(
    const float* __restrict__ key, const float* __restrict__ query, const float* __restrict__ value,
    const float* __restrict__ Wq, const float* __restrict__ Wk, const float* __restrict__ Wv,
    bf16* __restrict__ Qb, char* __restrict__ KV)
{
  __shared__ __align__(16) bf16 tile[128][72];   // pad 72 (16B-aligned rows)
  const int tid = threadIdx.x, w = tid >> 6, lane = tid & 63, l31 = lane & 31, lh = lane >> 5;
  const int r0 = blockIdx.x * 128;
  const int m0 = r0 + w * 32;

  #pragma unroll
  for (int p = 0; p < 3; ++p) {
    const float* X = (p == 0) ? query : (p == 1) ? key : value;
    const float* W = (p == 0) ? Wq    : (p == 1) ? Wk  : Wv;

    bf16x8 af[4];
    {
      const float* xr = X + (size_t)(m0 + l31) * 64 + 8 * lh;
      #pragma unroll
      for (int c = 0; c < 4; ++c) {
        f32x4 lo = *(const f32x4*)(xr + c * 16);
        f32x4 hi = *(const f32x4*)(xr + c * 16 + 4);
        bf16x8 v;
        #pragma unroll
        for (int j = 0; j < 4; ++j) { v[j] = (bf16)lo[j]; v[4 + j] = (bf16)hi[j]; }
        af[c] = v;
      }
    }
    bf16x8 bfr[2][4];
    #pragma unroll
    for (int nb = 0; nb < 2; ++nb) {
      const float* wr = W + (size_t)(l31 + 32 * nb) * 64 + 8 * lh;
      #pragma unroll
      for (int c = 0; c < 4; ++c) {
        f32x4 lo = *(const f32x4*)(wr + c * 16);
        f32x4 hi = *(const f32x4*)(wr + c * 16 + 4);
        bf16x8 v;
        #pragma unroll
        for (int j = 0; j < 4; ++j) { v[j] = (bf16)lo[j]; v[4 + j] = (bf16)hi[j]; }
        bfr[nb][c] = v;
      }
    }
    f32x16 a0, a1;
    #pragma unroll
    for (int r = 0; r < 16; ++r) { a0[r] = 0.f; a1[r] = 0.f; }
    #pragma unroll
    for (int c = 0; c < 4; ++c) {
      a0 = mfma32(af[c], bfr[0][c], a0);
      a1 = mfma32(af[c], bfr[1][c], a1);
    }

    const float qs = (p == 0) ? SCALE_LOG2E : 1.0f;
    __syncthreads();
    #pragma unroll
    for (int r = 0; r < 16; ++r) {
      const int row = w * 32 + (r & 3) + 8 * (r >> 2) + 4 * lh;
      tile[row][l31]      = (bf16)(a0[r] * qs);
      tile[row][l31 + 32] = (bf16)(a1[r] * qs);
    }
    __syncthreads();

    if (p == 0) {
      // Q: rows to [bh][s][64]
      const int rloc = tid >> 1, hf = tid & 1;
      const int rg = r0 + rloc, bs = rg >> 3, h = rg & 7, b = bs >> 12, sidx = bs & 4095;
      bf16* dst = Qb + (((size_t)(b * 8 + h) * SLEN + sidx) * 64 + hf * 32);
      const bf16* srcp = &tile[rloc][hf * 32];
      #pragma unroll
      for (int u = 0; u < 4; ++u) *(uint4v*)(dst + u * 8) = *(const uint4v*)(srcp + u * 8);
    } else if (p == 1) {
      // K -> fragment image
      const int b = blockIdx.x >> 8;
      const int s0 = (blockIdx.x & 255) * 16;
      #pragma unroll
      for (int u = 0; u < 4; ++u) {
        const int pid = u * 256 + tid;
        const int sl = pid & 15, h = (pid >> 4) & 7, plh = (pid >> 7) & 1, c = pid >> 8;
        const int s = s0 + sl;
        const int bh = b * 8 + h, hf2 = s >> 11, tt = (s >> 5) & 63, kl = s & 31;
        char* dst = KV + ((size_t)((bh * 2 + hf2) * 64 + tt) * 8192)
                       + c * 1024 + (kl + 32 * plh) * 16;
        *(uint4v*)dst = *(const uint4v*)&tile[sl * 8 + h][c * 16 + plh * 8];
      }
    } else {
      // V -> fragment image (column gather from tile)
      const int b = blockIdx.x >> 8;
      const int s0 = (blockIdx.x & 255) * 16;
      const int cc = (s0 >> 4) & 1;
      const int hf2 = s0 >> 11, tt = (s0 >> 5) & 63;
      #pragma unroll
      for (int u = 0; u < 4; ++u) {
        const int pid = u * 256 + tid;
        const int ld = pid & 31, db = (pid >> 5) & 1, plh = (pid >> 6) & 1, h = pid >> 7;
        const int d = db * 32 + ld;
        const int bh = b * 8 + h;
        unsigned wds[4];
        #pragma unroll
        for (int t2 = 0; t2 < 4; ++t2) {
          unsigned short ua = __builtin_bit_cast(unsigned short, tile[(plh * 8 + 2 * t2) * 8 + h][d]);
          unsigned short ub = __builtin_bit_cast(unsigned short, tile[(plh * 8 + 2 * t2 + 1) * 8 + h][d]);
          wds[t2] = (unsigned)ua | ((unsigned)ub << 16);
        }
        char* dst = KV + ((size_t)((bh * 2 + hf2) * 64 + tt) * 8192) + 4096
                       + (db * 2 + cc) * 1024 + (ld + 32 * plh) * 16;
        uint4v A; A[0] = wds[0]; A[1] = wds[1]; A[2] = wds[2]; A[3] = wds[3];
        *(uint4v*)dst = A;
      }
    }
  }
}

// ---------------- kernel 2: mask -> transposed remapped words ----------------
// MT[lh][q][64 words]: word t covers tile32 pair (2t, 2t+1);
// low16 bit r = mask[q][(2t)*32 + (r&3)+8*(r>>2)+4*lh], high16 same for tile 2t+1.
__device__ __forceinline__ unsigned nib_compress(unsigned x) {
  x = (x | (x >> 4)) & 0x00FF00FFu;
  x = (x | (x >> 8)) & 0x0000FFFFu;
  return x;
}
__global__ void pack_mask(const int* __restrict__ mask, unsigned* __restrict__ MT)
{
  const int w = threadIdx.x >> 6, lane = threadIdx.x & 63;
  const int q = blockIdx.x * 4 + w;
  const int* row = mask + (size_t)q * SLEN;
  unsigned long long mine = 0ull;
  #pragma unroll 4
  for (int i = 0; i < 64; ++i) {
    unsigned long long b = __ballot(row[i * 64 + lane] != 0);
    if (i == lane) mine = b;
  }
  const unsigned lo = (unsigned)mine, hi = (unsigned)(mine >> 32);
  const unsigned w0 = nib_compress(lo & 0x0F0F0F0Fu)        | (nib_compress(hi & 0x0F0F0F0Fu) << 16);
  const unsigned w1 = nib_compress((lo >> 4) & 0x0F0F0F0Fu) | (nib_compress((hi >> 4) & 0x0F0F0F0Fu) << 16);
  MT[((size_t)q) * 64 + lane] = w0;                       // lh = 0 plane
  MT[((size_t)(4096 + q)) * 64 + lane] = w1;              // lh = 1 plane
}

// ---------------- kernel 3: Wo -> hi/lo bf16 planes ----------------
__global__ void wo_split(const float* __restrict__ Wo, bf16* __restrict__ WH, bf16* __restrict__ WL)
{
  const int i = (blockIdx.x * 256 + threadIdx.x) * 4;
  f32x4 v = *(const f32x4*)(Wo + i);
  bf16x4 h, l;
  #pragma unroll
  for (int j = 0; j < 4; ++j) { h[j] = (bf16)v[j]; l[j] = (bf16)(v[j] - (float)h[j]); }
  *(bf16x4*)(WH + i) = h;
  *(bf16x4*)(WL + i) = l;
}

// ---------------- kernel 4: flash attention — barrier-free per-wave streaming ----------------
// Wave = 32 q rows x 2048 kv (split 2). No LDS / no __syncthreads in loop.
// K/V read from fragment image via wave-uniform SGPR base + lane offset (coalesced).
__global__ __launch_bounds__(256, 4) void attn_kernel(
    const bf16* __restrict__ Qb, const char* __restrict__ KV, const unsigned* __restrict__ MT,
    float* __restrict__ PO, float* __restrict__ PLg)
{
  __shared__ __align__(16) unsigned char smem[4][8448];  // per-wave transpose scratch

  const int tid = threadIdx.x, w = tid >> 6, lane = tid & 63, l31 = lane & 31, lh = lane >> 5;
  const int wid = blockIdx.x * 4 + w;
  const int qt = wid & 127, bh = (wid >> 7) & 15, half = wid >> 11;
  const int q0w = qt * 32;
  const int qrow = q0w + l31;

  // Q fragments (B operand): qf[c] elem j = Qs[qrow][16c + 8lh + j]
  const bf16* qp = Qb + ((size_t)bh * SLEN + qrow) * HDIM + 8 * lh;
  const bf16x8 qf0 = *(const bf16x8*)(qp);
  const bf16x8 qf1 = *(const bf16x8*)(qp + 16);
  const bf16x8 qf2 = *(const bf16x8*)(qp + 32);
  const bf16x8 qf3 = *(const bf16x8*)(qp + 48);

  // wave-uniform KV stream base, forced to SGPR
  const char* kb = KV + ((size_t)((bh * 2 + half) * 64) * 8192);
  {
    unsigned long long ka = (unsigned long long)kb;
    unsigned lo_ = __builtin_amdgcn_readfirstlane((unsigned)ka);
    unsigned hi_ = __builtin_amdgcn_readfirstlane((unsigned)(ka >> 32));
    kb = (const char*)(((unsigned long long)hi_ << 32) | (unsigned long long)lo_);
  }
  const int vo = lane * 16;

  // mask word stream (per-lane), 1 dwordx4 per 8 tiles, double-buffered
  const unsigned* mtp = MT + ((size_t)(lh * 4096 + qrow)) * 64 + half * 32;
  uint4v mw = *(const uint4v*)(mtp);

  f32x16 o0, o1;
  #pragma unroll
  for (int r = 0; r < 16; ++r) { o0[r] = 0.f; o1[r] = 0.f; }
  float la0 = 0.f, la1 = 0.f, la2 = 0.f, la3 = 0.f;

#define TILE32(WORD, SH) { \
  const bf16x8 kf0 = *(const bf16x8*)(kb + vo); \
  const bf16x8 kf1 = *(const bf16x8*)(kb + vo + 1024); \
  const bf16x8 kf2 = *(const bf16x8*)(kb + vo + 2048); \
  const bf16x8 kf3 = *(const bf16x8*)(kb + vo + 3072); \
  const bf16x8 vf0 = *(const bf16x8*)(kb + vo + 4096); \
  const bf16x8 vf1 = *(const bf16x8*)(kb + vo + 5120); \
  const bf16x8 vf2 = *(const bf16x8*)(kb + vo + 6144); \
  const bf16x8 vf3 = *(const bf16x8*)(kb + vo + 7168); \
  f32x16 s; \
  _Pragma("unroll") for (int r = 0; r < 16; ++r) s[r] = 0.f; \
  s = mfma32(kf0, qf0, s); s = mfma32(kf1, qf1, s); \
  s = mfma32(kf2, qf2, s); s = mfma32(kf3, qf3, s); \
  float p[16]; \
  _Pragma("unroll") for (int r = 0; r < 16; ++r) { \
    float e = __builtin_amdgcn_exp2f(s[r]); \
    unsigned kbit = (unsigned)(((int)((WORD) << (31 - (SH) - r))) >> 31); \
    e = __builtin_bit_cast(float, __builtin_bit_cast(unsigned, e) & kbit); \
    p[r] = e; \
    if ((r & 3) == 0) la0 += e; else if ((r & 3) == 1) la1 += e; \
    else if ((r & 3) == 2) la2 += e; else la3 += e; } \
  bf16x8 bp0, bp1; \
  { unsigned Wa = pk2(p[0], p[1]), Wb = pk2(p[2], p[3]); \
    unsigned Wc = pk2(p[4], p[5]), Wd = pk2(p[6], p[7]); \
    uint2v s02 = __builtin_amdgcn_permlane32_swap(Wa, Wc, false, false); \
    uint2v s13 = __builtin_amdgcn_permlane32_swap(Wb, Wd, false, false); \
    uint4v fw; fw[0] = s02[0]; fw[1] = s13[0]; fw[2] = s02[1]; fw[3] = s13[1]; \
    bp0 = __builtin_bit_cast(bf16x8, fw); } \
  { unsigned Wa = pk2(p[8], p[9]), Wb = pk2(p[10], p[11]); \
    unsigned Wc = pk2(p[12], p[13]), Wd = pk2(p[14], p[15]); \
    uint2v s02 = __builtin_amdgcn_permlane32_swap(Wa, Wc, false, false); \
    uint2v s13 = __builtin_amdgcn_permlane32_swap(Wb, Wd, false, false); \
    uint4v fw; fw[0] = s02[0]; fw[1] = s13[0]; fw[2] = s02[1]; fw[3] = s13[1]; \
    bp1 = __builtin_bit_cast(bf16x8, fw); } \
  o0 = mfma32(vf0, bp0, o0); \
  o0 = mfma32(vf1, bp1, o0); \
  o1 = mfma32(vf2, bp0, o1); \
  o1 = mfma32(vf3, bp1, o1); \
  kb += 8192; \
}

  for (int g = 0; g < 8; ++g) {
    const uint4v mwN = *(const uint4v*)(mtp + 4 * ((g < 7) ? g + 1 : 7));
    #pragma unroll
    for (int tp = 0; tp < 4; ++tp) {
      const unsigned word = mw[tp];
      TILE32(word, 0)
      TILE32(word, 16)
    }
    mw = mwN;
  }
#undef TILE32

  // ---- epilogue: wave-private transpose to [q][64] f32, store partials ----
  float plsum = (la0 + la1) + (la2 + la3);
  plsum += __shfl_xor(plsum, 32);

  float* T = (float*)(smem[w]);   // [32 q][65 f32]
  #pragma unroll
  for (int r = 0; r < 16; ++r) {
    const int dr = (r & 3) + 8 * (r >> 2) + 4 * lh;
    T[l31 * 65 + dr]      = o0[r];
    T[l31 * 65 + 32 + dr] = o1[r];
  }
  // wave-internal LDS dependency: compiler inserts lgkm wait before reads below
  const int q = lane >> 1, side = lane & 1;
  float* dst = PO + ((size_t)((half * 16 + bh) * SLEN + q0w + q)) * 64 + side * 32;
  const float* srcp = T + q * 65 + side * 32;
  #pragma unroll
  for (int u = 0; u < 8; ++u) *(f32x4*)(dst + u * 4) = *(const f32x4*)(srcp + u * 4);
  if (lane < 32) PLg[(size_t)(half * 16 + bh) * SLEN + q0w + l31] = plsum;
}

// ---------------- kernel 4b: combine the two kv halves ----------------
__global__ __launch_bounds__(256) void combine_halves(
    const float* __restrict__ PO, const float* __restrict__ PLg,
    bf16* __restrict__ CH, bf16* __restrict__ CL)
{
  const int bh = blockIdx.x >> 5, qt = blockIdx.x & 31;
  const int t = threadIdx.x;
  const int q = qt * 128 + (t >> 1);
  const size_t HOFF = (size_t)16 * SLEN * 64;
  const size_t base = ((size_t)bh * SLEN + q) * 64 + (t & 1) * 32;
  const float inv = 1.f / (PLg[(size_t)bh * SLEN + q] +
                           PLg[(size_t)16 * SLEN + (size_t)bh * SLEN + q]);
  const float* p0 = PO + base;
  const float* p1 = PO + HOFF + base;
  unsigned hw[16], lw[16];
  #pragma unroll
  for (int i = 0; i < 8; ++i) {
    f32x4 a = *(const f32x4*)(p0 + i * 4);
    f32x4 b = *(const f32x4*)(p1 + i * 4);
    float v0 = (a[0] + b[0]) * inv, v1 = (a[1] + b[1]) * inv;
    float v2 = (a[2] + b[2]) * inv, v3 = (a[3] + b[3]) * inv;
    float h0 = (float)(bf16)v0, h1 = (float)(bf16)v1;
    float h2 = (float)(bf16)v2, h3 = (float)(bf16)v3;
    hw[i * 2]     = pk2(v0, v1);
    hw[i * 2 + 1] = pk2(v2, v3);
    lw[i * 2]     = pk2(v0 - h0, v1 - h1);
    lw[i * 2 + 1] = pk2(v2 - h2, v3 - h3);
  }
  bf16* ch = CH + base;
  bf16* cl = CL + base;
  #pragma unroll
  for (int u = 0; u < 4; ++u) {
    uint4v H; H[0] = hw[u*4]; H[1] = hw[u*4+1]; H[2] = hw[u*4+2]; H[3] = hw[u*4+3];
    uint4v L; L[0] = lw[u*4]; L[1] = lw[u*4+1]; L[2] = lw[u*4+2]; L[3] = lw[u*4+3];
    *(uint4v*)(ch + u * 8) = H;
    *(uint4v*)(cl + u * 8) = L;
  }
}

// ---------------- kernel 5: output projection (hi/lo split GEMM) ----------------
__global__ __launch_bounds__(256, 2) void out_proj(
    const bf16* __restrict__ CH, const bf16* __restrict__ CL,
    const bf16* __restrict__ WH, const bf16* __restrict__ WL,
    const float* __restrict__ bo, float* __restrict__ out)
{
  __shared__ __align__(16) bf16 Af[2][4][4][64][8];  // 32KB
  const int tid = threadIdx.x, w = tid >> 6, lane = tid & 63, l31 = lane & 31, lh = lane >> 5;
  const int mt = blockIdx.x >> 3, nt = blockIdx.x & 7;
  const int bs0 = mt * 128, n0 = nt * 64;
  const int b = bs0 >> 12, sbase = bs0 & 4095;

  f32x16 a0, a1;
  #pragma unroll
  for (int r = 0; r < 16; ++r) { a0[r] = 0.f; a1[r] = 0.f; }

  for (int kk = 0; kk < 8; ++kk) {
    __syncthreads();
    #pragma unroll
    for (int qq = 0; qq < 8; ++qq) {
      const int fid = w * 8 + qq, pl = fid >> 4, mb = (fid >> 2) & 3, c = fid & 3;
      const bf16* src = (pl ? CL : CH) +
          ((size_t)(b * 8 + kk) * SLEN + sbase + 32 * mb + l31) * 64 + 16 * c + 8 * lh;
      cp16(src, &Af[pl][mb][c][0][0]);
    }
    __syncthreads();

    bf16x8 bh0[4], bl0[4], bh1[4], bl1[4], ah[4], al[4];
    #pragma unroll
    for (int c = 0; c < 4; ++c) {
      const size_t o0off = (size_t)(n0 + l31) * EMB + kk * 64 + 16 * c + 8 * lh;
      const size_t o1off = (size_t)(n0 + l31 + 32) * EMB + kk * 64 + 16 * c + 8 * lh;
      bh0[c] = *(const bf16x8*)(WH + o0off);
      bl0[c] = *(const bf16x8*)(WL + o0off);
      bh1[c] = *(const bf16x8*)(WH + o1off);
      bl1[c] = *(const bf16x8*)(WL + o1off);
      ah[c] = *(const bf16x8*)(&Af[0][w][c][lane][0]);
      al[c] = *(const bf16x8*)(&Af[1][w][c][lane][0]);
    }
    #pragma unroll
    for (int c = 0; c < 4; ++c) {
      a0 = mfma32(ah[c], bh0[c], a0);
      a0 = mfma32(ah[c], bl0[c], a0);
      a0 = mfma32(al[c], bh0[c], a0);
      a1 = mfma32(ah[c], bh1[c], a1);
      a1 = mfma32(ah[c], bl1[c], a1);
      a1 = mfma32(al[c], bh1[c], a1);
    }
  }

  const float bv0 = bo[n0 + l31], bv1 = bo[n0 + l31 + 32];
  #pragma unroll
  for (int r = 0; r < 16; ++r) {
    const int row = bs0 + w * 32 + (r & 3) + 8 * (r >> 2) + 4 * lh;
    out[(size_t)row * EMB + n0 + l31]      = a0[r] + bv0;
    out[(size_t)row * EMB + n0 + l31 + 32] = a1[r] + bv1;
  }
}

// ---------------- launch ----------------
extern "C" void kernel_launch(void* const* d_in, const int* in_sizes, int n_in,
                              void* d_out, int out_size, void* d_ws, size_t ws_size,
                              hipStream_t stream)
{
  (void)in_sizes; (void)n_in; (void)out_size; (void)ws_size;
  const float* key   = (const float*)d_in[0];
  const float* query = (const float*)d_in[1];
  const float* value = (const float*)d_in[2];
  const int*   mask  = (const int*)d_in[3];
  const float* Wq    = (const float*)d_in[4];
  const float* Wk    = (const float*)d_in[5];
  const float* Wv    = (const float*)d_in[6];
  const float* Wo    = (const float*)d_in[7];
  const float* bo    = (const float*)d_in[8];
  float* out = (float*)d_out;

  char* ws = (char*)d_ws;
  bf16* Qb = (bf16*)(ws);                        // 8 MB  [bh][s][64] pre-scaled
  char* KVimg = ws + (8ull << 20);               // 16 MB fragment image
  unsigned* MT = (unsigned*)(ws + (24ull << 20)); // 2 MB [lh][q][64 words]
  bf16* CH = (bf16*)(ws + (26ull << 20));        // 8 MB  ctx hi
  bf16* CL = (bf16*)(ws + (34ull << 20));        // 8 MB  ctx lo
  bf16* WH = (bf16*)(ws + (42ull << 20));        // 512 KB
  bf16* WL = (bf16*)(ws + (42ull << 20) + (512ull << 10));
  float* PO  = (float*)(ws + (44ull << 20));     // [2][16][4096][64] f32 = 33.6 MB
  float* PLg = (float*)(ws + (78ull << 20));     // [2][16][4096] f32

  proj_qkv<<<512, 256, 0, stream>>>(key, query, value, Wq, Wk, Wv, Qb, KVimg);
  pack_mask<<<1024, 256, 0, stream>>>(mask, MT);
  wo_split<<<256, 256, 0, stream>>>(Wo, WH, WL);
  attn_kernel<<<1024, 256, 0, stream>>>(Qb, KVimg, MT, PO, PLg);
  combine_halves<<<512, 256, 0, stream>>>(PO, PLg, CH, CL);
  out_proj<<<512, 256, 0, stream>>>(CH, CL, WH, WL, bo, out);
}

// Round 9
// 267.967 us; speedup vs baseline: 1.7534x; 1.7534x over previous
//
#include <hip/hip_runtime.h>

// ---------------- types / helpers ----------------
typedef __bf16 bf16;
typedef __attribute__((ext_vector_type(8)))  bf16     bf16x8;
typedef __attribute__((ext_vector_type(4)))  bf16     bf16x4;
typedef __attribute__((ext_vector_type(16))) float    f32x16;
typedef __attribute__((ext_vector_type(4)))  float    f32x4;
typedef __attribute__((ext_vector_type(4)))  unsigned uint4v;
typedef __attribute__((ext_vector_type(2)))  unsigned uint2v;

#define SLEN 4096
#define HDIM 64
#define EMB 512
#define NTILES 64
#define SCALE_LOG2E 0.1803336100254854f  /* 0.125 * log2(e), folded into Q at projection */

__device__ __forceinline__ f32x16 mfma32(bf16x8 a, bf16x8 b, f32x16 c) {
  return __builtin_amdgcn_mfma_f32_32x32x16_bf16(a, b, c, 0, 0, 0);
}

// async global->LDS, 16B per lane; LDS dest is wave-uniform base + lane*16
__device__ __forceinline__ void cp16(const void* g, const void* l) {
  __builtin_amdgcn_global_load_lds(
      (__attribute__((address_space(1))) unsigned int*)(unsigned long long)g,
      (__attribute__((address_space(3))) unsigned int*)(unsigned int)(unsigned long long)l,
      16, 0, 0);
}

__device__ __forceinline__ unsigned pk2(float a, float b) {
  unsigned short ua = __builtin_bit_cast(unsigned short, (bf16)a);
  unsigned short ub = __builtin_bit_cast(unsigned short, (bf16)b);
  return (unsigned)ua | ((unsigned)ub << 16);
}

// ---------------- kernel 1: QKV projections (MFMA), Q pre-scaled ----------------
__global__ __launch_bounds__(256, 2) void proj_qkv(
    const float* __restrict__ key, const float* __restrict__ query, const float* __restrict__ value,
    const float* __restrict__ Wq, const float* __restrict__ Wk, const float* __restrict__ Wv,
    bf16* __restrict__ Qb, bf16* __restrict__ Kb, bf16* __restrict__ VT)
{
  __shared__ __align__(16) bf16 tile[128][64];
  const int tid = threadIdx.x, w = tid >> 6, lane = tid & 63, l31 = lane & 31, lh = lane >> 5;
  const int r0 = blockIdx.x * 128;
  const int m0 = r0 + w * 32;

  #pragma unroll
  for (int p = 0; p < 3; ++p) {
    const float* X = (p == 0) ? query : (p == 1) ? key : value;
    const float* W = (p == 0) ? Wq    : (p == 1) ? Wk  : Wv;

    bf16x8 af[4];
    {
      const float* xr = X + (size_t)(m0 + l31) * 64 + 8 * lh;
      #pragma unroll
      for (int c = 0; c < 4; ++c) {
        f32x4 lo = *(const f32x4*)(xr + c * 16);
        f32x4 hi = *(const f32x4*)(xr + c * 16 + 4);
        bf16x8 v;
        #pragma unroll
        for (int j = 0; j < 4; ++j) { v[j] = (bf16)lo[j]; v[4 + j] = (bf16)hi[j]; }
        af[c] = v;
      }
    }
    bf16x8 bfr[2][4];
    #pragma unroll
    for (int nb = 0; nb < 2; ++nb) {
      const float* wr = W + (size_t)(l31 + 32 * nb) * 64 + 8 * lh;
      #pragma unroll
      for (int c = 0; c < 4; ++c) {
        f32x4 lo = *(const f32x4*)(wr + c * 16);
        f32x4 hi = *(const f32x4*)(wr + c * 16 + 4);
        bf16x8 v;
        #pragma unroll
        for (int j = 0; j < 4; ++j) { v[j] = (bf16)lo[j]; v[4 + j] = (bf16)hi[j]; }
        bfr[nb][c] = v;
      }
    }
    f32x16 a0, a1;
    #pragma unroll
    for (int r = 0; r < 16; ++r) { a0[r] = 0.f; a1[r] = 0.f; }
    #pragma unroll
    for (int c = 0; c < 4; ++c) {
      a0 = mfma32(af[c], bfr[0][c], a0);
      a1 = mfma32(af[c], bfr[1][c], a1);
    }

    const float qs = (p == 0) ? SCALE_LOG2E : 1.0f;
    __syncthreads();
    #pragma unroll
    for (int r = 0; r < 16; ++r) {
      const int row = w * 32 + (r & 3) + 8 * (r >> 2) + 4 * lh;
      tile[row][l31]      = (bf16)(a0[r] * qs);
      tile[row][l31 + 32] = (bf16)(a1[r] * qs);
    }
    __syncthreads();

    if (p < 2) {
      bf16* OUT = p ? Kb : Qb;
      const int rloc = tid >> 1, hf = tid & 1;
      const int rg = r0 + rloc, bs = rg >> 3, h = rg & 7, b = bs >> 12, sidx = bs & 4095;
      bf16* dst = OUT + (((size_t)(b * 8 + h) * SLEN + sidx) * 64 + hf * 32);
      const bf16* srcp = &tile[rloc][hf * 32];
      #pragma unroll
      for (int u = 0; u < 4; ++u) *(uint4v*)(dst + u * 8) = *(const uint4v*)(srcp + u * 8);
    } else {
      const int h = tid >> 5, d0 = tid & 31;
      const int b = blockIdx.x >> 8, s0 = (blockIdx.x * 16) & 4095;
      #pragma unroll
      for (int dh = 0; dh < 2; ++dh) {
        const int dd = d0 + 32 * dh;
        unsigned pk4[8];
        #pragma unroll
        for (int t2 = 0; t2 < 8; ++t2) {
          unsigned short ua = __builtin_bit_cast(unsigned short, tile[(2 * t2) * 8 + h][dd]);
          unsigned short ub = __builtin_bit_cast(unsigned short, tile[(2 * t2 + 1) * 8 + h][dd]);
          pk4[t2] = (unsigned)ua | ((unsigned)ub << 16);
        }
        bf16* dst = VT + ((size_t)(b * 8 + h) * 64 + dd) * SLEN + s0;
        uint4v A; A[0] = pk4[0]; A[1] = pk4[1]; A[2] = pk4[2]; A[3] = pk4[3];
        uint4v Bv; Bv[0] = pk4[4]; Bv[1] = pk4[5]; Bv[2] = pk4[6]; Bv[3] = pk4[7];
        *(uint4v*)(dst) = A;
        *(uint4v*)(dst + 8) = Bv;
      }
    }
  }
}

// ---------------- kernel 2: mask -> remapped 32-bit words ----------------
// MW[lh][tile][q] : bit (kc*16 + r) = mask[q][tile*64 + kc*32 + (r&3)+8*(r>>2)+4*lh]
__device__ __forceinline__ unsigned nib_compress(unsigned x) {
  x = (x | (x >> 4)) & 0x00FF00FFu;
  x = (x | (x >> 8)) & 0x0000FFFFu;
  return x;
}
__global__ void pack_mask(const int* __restrict__ mask, unsigned* __restrict__ MW)
{
  const int w = threadIdx.x >> 6, lane = threadIdx.x & 63;
  const int q = blockIdx.x * 4 + w;
  const int* row = mask + (size_t)q * SLEN;
  unsigned long long mine = 0ull;
  #pragma unroll 4
  for (int i = 0; i < 64; ++i) {
    unsigned long long b = __ballot(row[i * 64 + lane] != 0);
    if (i == lane) mine = b;
  }
  const unsigned lo = (unsigned)mine, hi = (unsigned)(mine >> 32);
  const unsigned w0 = nib_compress(lo & 0x0F0F0F0Fu)        | (nib_compress(hi & 0x0F0F0F0Fu) << 16);
  const unsigned w1 = nib_compress((lo >> 4) & 0x0F0F0F0Fu) | (nib_compress((hi >> 4) & 0x0F0F0F0Fu) << 16);
  MW[(size_t)lane * SLEN + q] = w0;                              // lh = 0 plane
  MW[(size_t)NTILES * SLEN + (size_t)lane * SLEN + q] = w1;      // lh = 1 plane
}

// ---------------- kernel 3: Wo -> hi/lo bf16 planes ----------------
__global__ void wo_split(const float* __restrict__ Wo, bf16* __restrict__ WH, bf16* __restrict__ WL)
{
  const int i = (blockIdx.x * 256 + threadIdx.x) * 4;
  f32x4 v = *(const f32x4*)(Wo + i);
  bf16x4 h, l;
  #pragma unroll
  for (int j = 0; j < 4; ++j) { h[j] = (bf16)v[j]; l[j] = (bf16)(v[j] - (float)h[j]); }
  *(bf16x4*)(WH + i) = h;
  *(bf16x4*)(WL + i) = l;
}

// ---------------- kernel 4: flash attention, triple-buffered counted-vmcnt pipeline ----
// wave w: q-group (w&1), kv-chunk (w>>1). Max-free softmax => partials linear.
// 3 LDS buffers x 16KB (K 8K + V 8K); cp16 staging issued 2 tiles ahead.
// Per tile: 4x cp16 (manual vmcnt(4) accounting) + 1 plain C++ mask load
// (backend-tracked: compiler inserts the exact wait for the mask value).
// vmcnt(4) at body top always retires tile t's 4 cp16 regardless of where the
// scheduler places mask loads (ops after them = C(t+1)x4 + 0..2 masks >= 4).
__global__ __launch_bounds__(256, 3) void attn_kernel(
    const bf16* __restrict__ Qb, const bf16* __restrict__ Kb, const bf16* __restrict__ VT,
    const unsigned* __restrict__ MW,
    bf16* __restrict__ ctxh, bf16* __restrict__ ctxl)
{
  __shared__ __align__(16) unsigned char smem[49152];

  const int tid = threadIdx.x, w = tid >> 6, lane = tid & 63, l31 = lane & 31, lh = lane >> 5;
  const int qg = w & 1, kc = w >> 1;
  const int bh = blockIdx.x >> 6, qt = blockIdx.x & 63;
  const int q0 = qt * 64;
  const int qrow = q0 + qg * 32 + l31;
  const int lh4 = 4 * lh;
  const int kcs = kc << 4;

  // Q fragments (B operand: lane&31 = q, k-slot = 16c+8lh+j), pre-scaled
  const bf16* qp = Qb + ((size_t)bh * SLEN + qrow) * HDIM + 8 * lh;
  const bf16x8 qf0 = *(const bf16x8*)(qp);
  const bf16x8 qf1 = *(const bf16x8*)(qp + 16);
  const bf16x8 qf2 = *(const bf16x8*)(qp + 32);
  const bf16x8 qf3 = *(const bf16x8*)(qp + 48);

  // staging sources: wave stages K frags {2w,2w+1}, V frags {2w,2w+1} (frag f = mb*4+c)
  const int f0 = 2 * w, f1 = 2 * w + 1;
  const bf16* kp0 = Kb + ((size_t)bh * SLEN + (f0 >> 2) * 32 + l31) * HDIM + (f0 & 3) * 16 + 8 * lh;
  const bf16* kp1 = Kb + ((size_t)bh * SLEN + (f1 >> 2) * 32 + l31) * HDIM + (f1 & 3) * 16 + 8 * lh;
  const bf16* vp0 = VT + ((size_t)bh * HDIM + (f0 >> 2) * 32 + l31) * SLEN + (f0 & 3) * 16 + 8 * lh;
  const bf16* vp1 = VT + ((size_t)bh * HDIM + (f1 >> 2) * 32 + l31) * SLEN + (f1 & 3) * 16 + 8 * lh;

  // rotating buffers: [K 8K | V 8K] each
  unsigned char* sA = smem;
  unsigned char* sB = smem + 16384;
  unsigned char* sC = smem + 32768;
  const int fko = f0 * 1024;             // staging K dst offset within buffer (wave-uniform)
  const int fvo = 8192 + f0 * 1024;      // staging V dst offset
  const int lb = lane * 16;
  const int kroff = kc * 4096 + lb;      // read base offsets (per-lane)
  const int vroff = 8192 + kc * 2048 + lb;

  f32x16 o0, o1, Z16;
  #pragma unroll
  for (int r = 0; r < 16; ++r) { o0[r] = 0.f; o1[r] = 0.f; Z16[r] = 0.f; }
  float la0 = 0.f, la1 = 0.f, la2 = 0.f, la3 = 0.f;

  // mask stream: compiler-tracked loads, 1 tile ahead; mp points at mask(t+1)
  const unsigned* mp = MW + (size_t)lh * NTILES * SLEN + qrow;

  // prologue: stage tiles 0,1 -> sA,sB; load mask 0
  cp16(kp0, sA + fko); cp16(kp1, sA + fko + 1024);
  cp16(vp0, sA + fvo); cp16(vp1, sA + fvo + 1024);
  kp0 += 4096; kp1 += 4096; vp0 += 64; vp1 += 64;
  unsigned mwc = *mp;           // mask(0), tracked load
  mp += SLEN;                   // now points at mask(1)
  cp16(kp0, sB + fko); cp16(kp1, sB + fko + 1024);
  cp16(vp0, sB + fvo); cp16(vp1, sB + fvo + 1024);
  kp0 += 4096; kp1 += 4096; vp0 += 64; vp1 += 64;

  for (int t = 0; t < NTILES; ++t) {
    // retire tile t's 4 cp16 (tile t+1's stay in flight); then block barrier
    asm volatile("s_waitcnt vmcnt(4)" ::: "memory");
    __builtin_amdgcn_sched_barrier(0);
    __builtin_amdgcn_s_barrier();

    // prefetch mask(t+1) (tracked; backend inserts exact wait before its use)
    const unsigned mwn = *mp;
    mp += SLEN;

    // stage tile t+2 -> sC (dummy reads past the end land in allocated ws, unused)
    cp16(kp0, sC + fko); cp16(kp1, sC + fko + 1024);
    cp16(vp0, sC + fvo); cp16(vp1, sC + fvo + 1024);
    kp0 += 4096; kp1 += 4096; vp0 += 64; vp1 += 64;

    const unsigned char* kr = sA + kroff;
    const unsigned char* vr = sA + vroff;

    __builtin_amdgcn_s_setprio(1);
    f32x16 s = mfma32(*(const bf16x8*)(kr), qf0, Z16);
    s = mfma32(*(const bf16x8*)(kr + 1024), qf1, s);
    s = mfma32(*(const bf16x8*)(kr + 2048), qf2, s);
    s = mfma32(*(const bf16x8*)(kr + 3072), qf3, s);
    __builtin_amdgcn_s_setprio(0);

    const unsigned mwk = mwc >> kcs;
    float p[16];
    #pragma unroll
    for (int r = 0; r < 16; ++r) {
      float e = __builtin_amdgcn_exp2f(s[r]);
      unsigned kbit = (unsigned)(((int)(mwk << (31 - r))) >> 31);
      e = __builtin_bit_cast(float, __builtin_bit_cast(unsigned, e) & kbit);
      p[r] = e;
      if ((r & 3) == 0) la0 += e; else if ((r & 3) == 1) la1 += e;
      else if ((r & 3) == 2) la2 += e; else la3 += e;
    }

    bf16x8 bp0, bp1;
    {
      unsigned Wa = pk2(p[0], p[1]), Wb = pk2(p[2], p[3]);
      unsigned Wc = pk2(p[4], p[5]), Wd = pk2(p[6], p[7]);
      uint2v s02 = __builtin_amdgcn_permlane32_swap(Wa, Wc, false, false);
      uint2v s13 = __builtin_amdgcn_permlane32_swap(Wb, Wd, false, false);
      uint4v fw; fw[0] = s02[0]; fw[1] = s13[0]; fw[2] = s02[1]; fw[3] = s13[1];
      bp0 = __builtin_bit_cast(bf16x8, fw);
    }
    {
      unsigned Wa = pk2(p[8], p[9]), Wb = pk2(p[10], p[11]);
      unsigned Wc = pk2(p[12], p[13]), Wd = pk2(p[14], p[15]);
      uint2v s02 = __builtin_amdgcn_permlane32_swap(Wa, Wc, false, false);
      uint2v s13 = __builtin_amdgcn_permlane32_swap(Wb, Wd, false, false);
      uint4v fw; fw[0] = s02[0]; fw[1] = s13[0]; fw[2] = s02[1]; fw[3] = s13[1];
      bp1 = __builtin_bit_cast(bf16x8, fw);
    }

    __builtin_amdgcn_s_setprio(1);
    o0 = mfma32(*(const bf16x8*)(vr), bp0, o0);
    o0 = mfma32(*(const bf16x8*)(vr + 1024), bp1, o0);
    o1 = mfma32(*(const bf16x8*)(vr + 4096), bp0, o1);
    o1 = mfma32(*(const bf16x8*)(vr + 4096 + 1024), bp1, o1);
    __builtin_amdgcn_s_setprio(0);

    { unsigned char* tmp_ = sA; sA = sB; sB = sC; sC = tmp_; }
    mwc = mwn;   // plain register copy of a TRACKED load value (backend-safe)
  }

  // drain dummy stages before reusing LDS
  asm volatile("s_waitcnt vmcnt(0)" ::: "memory");
  __builtin_amdgcn_s_barrier();

  // ---- combine kv-chunk partners in LDS, normalize, hi/lo, transpose, write ----
  float plsum = (la0 + la1) + (la2 + la3);
  plsum += __shfl_xor(plsum, 32);

  float* POl = (float*)smem;             // [2][32][64] f32 = 16KB
  float* PLl = (float*)(smem + 16384);   // [2][64]

  if (w >= 2) {
    const int pw = w - 2;
    #pragma unroll
    for (int r = 0; r < 16; ++r) {
      POl[(pw * 32 + r) * 64 + lane]      = o0[r];
      POl[(pw * 32 + 16 + r) * 64 + lane] = o1[r];
    }
    PLl[pw * 64 + lane] = plsum;
  }
  __syncthreads();
  if (w < 2) {
    #pragma unroll
    for (int r = 0; r < 16; ++r) {
      o0[r] += POl[(w * 32 + r) * 64 + lane];
      o1[r] += POl[(w * 32 + 16 + r) * 64 + lane];
    }
    plsum += PLl[w * 64 + lane];
    const float inv = 1.f / plsum;
    #pragma unroll
    for (int r = 0; r < 16; ++r) { o0[r] *= inv; o1[r] *= inv; }
  }
  __syncthreads();

  bf16* Tr = (bf16*)(smem + 17408);   // [64][72]
  if (w < 2) {
    #pragma unroll
    for (int r = 0; r < 16; ++r) {
      const int dr = (r & 3) + 8 * (r >> 2) + lh4;
      Tr[(w * 32 + l31) * 72 + dr]      = (bf16)o0[r];
      Tr[(w * 32 + l31) * 72 + 32 + dr] = (bf16)o1[r];
    }
  }
  __syncthreads();
  if (tid < 128) {
    const int rloc = tid >> 1, hf = tid & 1;
    bf16* dst = ctxh + ((size_t)bh * SLEN + q0 + rloc) * 64 + hf * 32;
    const bf16* srcp = Tr + rloc * 72 + hf * 32;
    #pragma unroll
    for (int u = 0; u < 4; ++u) *(uint4v*)(dst + u * 8) = *(const uint4v*)(srcp + u * 8);
  }
  __syncthreads();
  if (w < 2) {
    #pragma unroll
    for (int r = 0; r < 16; ++r) {
      const int dr = (r & 3) + 8 * (r >> 2) + lh4;
      const float h0 = (float)(bf16)o0[r];
      const float h1 = (float)(bf16)o1[r];
      Tr[(w * 32 + l31) * 72 + dr]      = (bf16)(o0[r] - h0);
      Tr[(w * 32 + l31) * 72 + 32 + dr] = (bf16)(o1[r] - h1);
    }
  }
  __syncthreads();
  if (tid < 128) {
    const int rloc = tid >> 1, hf = tid & 1;
    bf16* dst = ctxl + ((size_t)bh * SLEN + q0 + rloc) * 64 + hf * 32;
    const bf16* srcp = Tr + rloc * 72 + hf * 32;
    #pragma unroll
    for (int u = 0; u < 4; ++u) *(uint4v*)(dst + u * 8) = *(const uint4v*)(srcp + u * 8);
  }
}

// ---------------- kernel 5: output projection (hi/lo split GEMM) ----------------
__global__ __launch_bounds__(256, 2) void out_proj(
    const bf16* __restrict__ CH, const bf16* __restrict__ CL,
    const bf16* __restrict__ WH, const bf16* __restrict__ WL,
    const float* __restrict__ bo, float* __restrict__ out)
{
  __shared__ __align__(16) bf16 Af[2][4][4][64][8];  // 32KB
  const int tid = threadIdx.x, w = tid >> 6, lane = tid & 63, l31 = lane & 31, lh = lane >> 5;
  const int mt = blockIdx.x >> 3, nt = blockIdx.x & 7;
  const int bs0 = mt * 128, n0 = nt * 64;
  const int b = bs0 >> 12, sbase = bs0 & 4095;

  f32x16 a0, a1;
  #pragma unroll
  for (int r = 0; r < 16; ++r) { a0[r] = 0.f; a1[r] = 0.f; }

  for (int kk = 0; kk < 8; ++kk) {
    __syncthreads();
    #pragma unroll
    for (int qq = 0; qq < 8; ++qq) {
      const int fid = w * 8 + qq, pl = fid >> 4, mb = (fid >> 2) & 3, c = fid & 3;
      const bf16* src = (pl ? CL : CH) +
          ((size_t)(b * 8 + kk) * SLEN + sbase + 32 * mb + l31) * 64 + 16 * c + 8 * lh;
      cp16(src, &Af[pl][mb][c][0][0]);
    }
    __syncthreads();

    bf16x8 bh0[4], bl0[4], bh1[4], bl1[4], ah[4], al[4];
    #pragma unroll
    for (int c = 0; c < 4; ++c) {
      const size_t o0off = (size_t)(n0 + l31) * EMB + kk * 64 + 16 * c + 8 * lh;
      const size_t o1off = (size_t)(n0 + l31 + 32) * EMB + kk * 64 + 16 * c + 8 * lh;
      bh0[c] = *(const bf16x8*)(WH + o0off);
      bl0[c] = *(const bf16x8*)(WL + o0off);
      bh1[c] = *(const bf16x8*)(WH + o1off);
      bl1[c] = *(const bf16x8*)(WL + o1off);
      ah[c] = *(const bf16x8*)(&Af[0][w][c][lane][0]);
      al[c] = *(const bf16x8*)(&Af[1][w][c][lane][0]);
    }
    #pragma unroll
    for (int c = 0; c < 4; ++c) {
      a0 = mfma32(ah[c], bh0[c], a0);
      a0 = mfma32(ah[c], bl0[c], a0);
      a0 = mfma32(al[c], bh0[c], a0);
      a1 = mfma32(ah[c], bh1[c], a1);
      a1 = mfma32(ah[c], bl1[c], a1);
      a1 = mfma32(al[c], bh1[c], a1);
    }
  }

  const float bv0 = bo[n0 + l31], bv1 = bo[n0 + l31 + 32];
  #pragma unroll
  for (int r = 0; r < 16; ++r) {
    const int row = bs0 + w * 32 + (r & 3) + 8 * (r >> 2) + 4 * lh;
    out[(size_t)row * EMB + n0 + l31]      = a0[r] + bv0;
    out[(size_t)row * EMB + n0 + l31 + 32] = a1[r] + bv1;
  }
}

// ---------------- launch ----------------
extern "C" void kernel_launch(void* const* d_in, const int* in_sizes, int n_in,
                              void* d_out, int out_size, void* d_ws, size_t ws_size,
                              hipStream_t stream)
{
  (void)in_sizes; (void)n_in; (void)out_size; (void)ws_size;
  const float* key   = (const float*)d_in[0];
  const float* query = (const float*)d_in[1];
  const float* value = (const float*)d_in[2];
  const int*   mask  = (const int*)d_in[3];
  const float* Wq    = (const float*)d_in[4];
  const float* Wk    = (const float*)d_in[5];
  const float* Wv    = (const float*)d_in[6];
  const float* Wo    = (const float*)d_in[7];
  const float* bo    = (const float*)d_in[8];
  float* out = (float*)d_out;

  char* ws = (char*)d_ws;                       // ~43.5 MB used
  bf16* Qb = (bf16*)(ws);                       // 8 MB  [BH][S][64] (pre-scaled)
  bf16* Kb = (bf16*)(ws + (8ull  << 20));       // 8 MB  [BH][S][64]
  bf16* VT = (bf16*)(ws + (16ull << 20));       // 8 MB  [BH][64][S]
  unsigned* MW = (unsigned*)(ws + (24ull << 20));  // 2 MB [lh][tile][q]
  bf16* CH = (bf16*)(ws + (26ull << 20));       // 8 MB  ctx hi
  bf16* CL = (bf16*)(ws + (34ull << 20));       // 8 MB  ctx lo
  bf16* WH = (bf16*)(ws + (42ull << 20));       // 512 KB
  bf16* WL = (bf16*)(ws + (42ull << 20) + (512ull << 10));

  proj_qkv<<<512, 256, 0, stream>>>(key, query, value, Wq, Wk, Wv, Qb, Kb, VT);
  pack_mask<<<1024, 256, 0, stream>>>(mask, MW);
  wo_split<<<256, 256, 0, stream>>>(Wo, WH, WL);
  attn_kernel<<<1024, 256, 0, stream>>>(Qb, Kb, VT, MW, CH, CL);
  out_proj<<<512, 256, 0, stream>>>(CH, CL, WH, WL, bo, out);
}

// Round 11
// 236.978 us; speedup vs baseline: 1.9826x; 1.1308x over previous
//
#include <hip/hip_runtime.h>

// ---------------- types / helpers ----------------
typedef __bf16 bf16;
typedef __attribute__((ext_vector_type(8)))  bf16     bf16x8;
typedef __attribute__((ext_vector_type(4)))  bf16     bf16x4;
typedef __attribute__((ext_vector_type(16))) float    f32x16;
typedef __attribute__((ext_vector_type(4)))  float    f32x4;
typedef __attribute__((ext_vector_type(4)))  unsigned uint4v;
typedef __attribute__((ext_vector_type(2)))  unsigned uint2v;

#define SLEN 4096
#define HDIM 64
#define EMB 512
#define NTILES 64            /* 64-kv tile count (mask word granularity) */
#define SCALE_LOG2E 0.1803336100254854f  /* 0.125 * log2(e), folded into Q at projection */

__device__ __forceinline__ f32x16 mfma32(bf16x8 a, bf16x8 b, f32x16 c) {
  return __builtin_amdgcn_mfma_f32_32x32x16_bf16(a, b, c, 0, 0, 0);
}

// async global->LDS, 16B per lane; LDS dest is wave-uniform base + lane*16
__device__ __forceinline__ void cp16(const void* g, const void* l) {
  __builtin_amdgcn_global_load_lds(
      (__attribute__((address_space(1))) unsigned int*)(unsigned long long)g,
      (__attribute__((address_space(3))) unsigned int*)(unsigned int)(unsigned long long)l,
      16, 0, 0);
}

__device__ __forceinline__ unsigned pk2(float a, float b) {
  unsigned short ua = __builtin_bit_cast(unsigned short, (bf16)a);
  unsigned short ub = __builtin_bit_cast(unsigned short, (bf16)b);
  return (unsigned)ua | ((unsigned)ub << 16);
}

// ---------------- kernel 1: QKV projections (MFMA), Q pre-scaled ----------------
__global__ __launch_bounds__(256, 2) void proj_qkv(
    const float* __restrict__ key, const float* __restrict__ query, const float* __restrict__ value,
    const float* __restrict__ Wq, const float* __restrict__ Wk, const float* __restrict__ Wv,
    bf16* __restrict__ Qb, bf16* __restrict__ Kb, bf16* __restrict__ VT)
{
  __shared__ __align__(16) bf16 tile[128][64];
  const int tid = threadIdx.x, w = tid >> 6, lane = tid & 63, l31 = lane & 31, lh = lane >> 5;
  const int r0 = blockIdx.x * 128;
  const int m0 = r0 + w * 32;

  #pragma unroll
  for (int p = 0; p < 3; ++p) {
    const float* X = (p == 0) ? query : (p == 1) ? key : value;
    const float* W = (p == 0) ? Wq    : (p == 1) ? Wk  : Wv;

    bf16x8 af[4];
    {
      const float* xr = X + (size_t)(m0 + l31) * 64 + 8 * lh;
      #pragma unroll
      for (int c = 0; c < 4; ++c) {
        f32x4 lo = *(const f32x4*)(xr + c * 16);
        f32x4 hi = *(const f32x4*)(xr + c * 16 + 4);
        bf16x8 v;
        #pragma unroll
        for (int j = 0; j < 4; ++j) { v[j] = (bf16)lo[j]; v[4 + j] = (bf16)hi[j]; }
        af[c] = v;
      }
    }
    bf16x8 bfr[2][4];
    #pragma unroll
    for (int nb = 0; nb < 2; ++nb) {
      const float* wr = W + (size_t)(l31 + 32 * nb) * 64 + 8 * lh;
      #pragma unroll
      for (int c = 0; c < 4; ++c) {
        f32x4 lo = *(const f32x4*)(wr + c * 16);
        f32x4 hi = *(const f32x4*)(wr + c * 16 + 4);
        bf16x8 v;
        #pragma unroll
        for (int j = 0; j < 4; ++j) { v[j] = (bf16)lo[j]; v[4 + j] = (bf16)hi[j]; }
        bfr[nb][c] = v;
      }
    }
    f32x16 a0, a1;
    #pragma unroll
    for (int r = 0; r < 16; ++r) { a0[r] = 0.f; a1[r] = 0.f; }
    #pragma unroll
    for (int c = 0; c < 4; ++c) {
      a0 = mfma32(af[c], bfr[0][c], a0);
      a1 = mfma32(af[c], bfr[1][c], a1);
    }

    const float qs = (p == 0) ? SCALE_LOG2E : 1.0f;
    __syncthreads();
    #pragma unroll
    for (int r = 0; r < 16; ++r) {
      const int row = w * 32 + (r & 3) + 8 * (r >> 2) + 4 * lh;
      tile[row][l31]      = (bf16)(a0[r] * qs);
      tile[row][l31 + 32] = (bf16)(a1[r] * qs);
    }
    __syncthreads();

    if (p < 2) {
      bf16* OUT = p ? Kb : Qb;
      const int rloc = tid >> 1, hf = tid & 1;
      const int rg = r0 + rloc, bs = rg >> 3, h = rg & 7, b = bs >> 12, sidx = bs & 4095;
      bf16* dst = OUT + (((size_t)(b * 8 + h) * SLEN + sidx) * 64 + hf * 32);
      const bf16* srcp = &tile[rloc][hf * 32];
      #pragma unroll
      for (int u = 0; u < 4; ++u) *(uint4v*)(dst + u * 8) = *(const uint4v*)(srcp + u * 8);
    } else {
      const int h = tid >> 5, d0 = tid & 31;
      const int b = blockIdx.x >> 8, s0 = (blockIdx.x * 16) & 4095;
      #pragma unroll
      for (int dh = 0; dh < 2; ++dh) {
        const int dd = d0 + 32 * dh;
        unsigned pk4[8];
        #pragma unroll
        for (int t2 = 0; t2 < 8; ++t2) {
          unsigned short ua = __builtin_bit_cast(unsigned short, tile[(2 * t2) * 8 + h][dd]);
          unsigned short ub = __builtin_bit_cast(unsigned short, tile[(2 * t2 + 1) * 8 + h][dd]);
          pk4[t2] = (unsigned)ua | ((unsigned)ub << 16);
        }
        bf16* dst = VT + ((size_t)(b * 8 + h) * 64 + dd) * SLEN + s0;
        uint4v A; A[0] = pk4[0]; A[1] = pk4[1]; A[2] = pk4[2]; A[3] = pk4[3];
        uint4v Bv; Bv[0] = pk4[4]; Bv[1] = pk4[5]; Bv[2] = pk4[6]; Bv[3] = pk4[7];
        *(uint4v*)(dst) = A;
        *(uint4v*)(dst + 8) = Bv;
      }
    }
  }
}

// ---------------- kernel 2: mask -> remapped 32-bit words ----------------
// MW[lh][tile64][q] : bit (kc*16 + r) = mask[q][tile64*64 + kc*32 + (r&3)+8*(r>>2)+4*lh]
__device__ __forceinline__ unsigned nib_compress(unsigned x) {
  x = (x | (x >> 4)) & 0x00FF00FFu;
  x = (x | (x >> 8)) & 0x0000FFFFu;
  return x;
}
__global__ void pack_mask(const int* __restrict__ mask, unsigned* __restrict__ MW)
{
  const int w = threadIdx.x >> 6, lane = threadIdx.x & 63;
  const int q = blockIdx.x * 4 + w;
  const int* row = mask + (size_t)q * SLEN;
  unsigned long long mine = 0ull;
  #pragma unroll 4
  for (int i = 0; i < 64; ++i) {
    unsigned long long b = __ballot(row[i * 64 + lane] != 0);
    if (i == lane) mine = b;
  }
  const unsigned lo = (unsigned)mine, hi = (unsigned)(mine >> 32);
  const unsigned w0 = nib_compress(lo & 0x0F0F0F0Fu)        | (nib_compress(hi & 0x0F0F0F0Fu) << 16);
  const unsigned w1 = nib_compress((lo >> 4) & 0x0F0F0F0Fu) | (nib_compress((hi >> 4) & 0x0F0F0F0Fu) << 16);
  MW[(size_t)lane * SLEN + q] = w0;                              // lh = 0 plane
  MW[(size_t)NTILES * SLEN + (size_t)lane * SLEN + q] = w1;      // lh = 1 plane
}

// ---------------- kernel 3: Wo -> hi/lo bf16 planes ----------------
__global__ void wo_split(const float* __restrict__ Wo, bf16* __restrict__ WH, bf16* __restrict__ WL)
{
  const int i = (blockIdx.x * 256 + threadIdx.x) * 4;
  f32x4 v = *(const f32x4*)(Wo + i);
  bf16x4 h, l;
  #pragma unroll
  for (int j = 0; j < 4; ++j) { h[j] = (bf16)v[j]; l[j] = (bf16)(v[j] - (float)h[j]); }
  *(bf16x4*)(WH + i) = h;
  *(bf16x4*)(WL + i) = l;
}

// ---------------- kernel 4: flash attention — 2-wave blocks, KVBLK=32, counted vmcnt ----
// Block: 2 waves x 32 q rows (64 q), full KV per wave. 16KB LDS: buf[2] x [K 4K | V 4K].
// Wave w stages K frags {2w,2w+1} + V frags {2w,2w+1} (4 cp16); both waves read all 8.
// Per tile: STAGE(next) -> vmcnt(4) -> s_barrier -> TILEC -> s_barrier (read-complete).
// The second barrier is the r10 race fix: buffer overwrite provably after all reads.
__global__ __launch_bounds__(128, 4) void attn_kernel(
    const bf16* __restrict__ Qb, const bf16* __restrict__ Kb, const bf16* __restrict__ VT,
    const unsigned* __restrict__ MW,
    bf16* __restrict__ ctxh, bf16* __restrict__ ctxl)
{
  __shared__ __align__(16) unsigned char smem[16384];

  const int tid = threadIdx.x, w = tid >> 6, lane = tid & 63, l31 = lane & 31, lh = lane >> 5;
  // XCD swizzle: dispatch d -> XCD d%8; each XCD gets a contiguous 128-block chunk
  // (2 bh's => 2MB KV working set fits the 4MB per-XCD L2). 1024 % 8 == 0: bijective.
  const int logical = (blockIdx.x & 7) * 128 + (blockIdx.x >> 3);
  const int bh = logical >> 6, qt = logical & 63;
  const int q0w = qt * 64 + w * 32;
  const int qrow = q0w + l31;
  const int lh4 = 4 * lh;

  // Q fragments (B operand: lane&31 = q, k-slot = 16c+8lh+j), pre-scaled
  const bf16* qp = Qb + ((size_t)bh * SLEN + qrow) * HDIM + 8 * lh;
  const bf16x8 qf0 = *(const bf16x8*)(qp);
  const bf16x8 qf1 = *(const bf16x8*)(qp + 16);
  const bf16x8 qf2 = *(const bf16x8*)(qp + 32);
  const bf16x8 qf3 = *(const bf16x8*)(qp + 48);

  // staging sources (tile kv0 = 0); wave w owns K frags c={2w,2w+1}, V frags f={2w,2w+1}
  const bf16* kp0 = Kb + ((size_t)bh * SLEN + l31) * HDIM + (2 * w) * 16 + 8 * lh;
  const bf16* kp1 = kp0 + 16;
  const bf16* vp0 = VT + ((size_t)bh * HDIM + w * 32 + l31) * SLEN + 8 * lh;
  const bf16* vp1 = vp0 + 16;

  const int fk = 2 * w * 1024;          // K staging dst offset within buffer
  const int fv = 4096 + 2 * w * 1024;   // V staging dst offset
  const int lb = lane * 16;

  f32x16 o0, o1, Z16;
  #pragma unroll
  for (int r = 0; r < 16; ++r) { o0[r] = 0.f; o1[r] = 0.f; Z16[r] = 0.f; }
  float la0 = 0.f, la1 = 0.f, la2 = 0.f, la3 = 0.f;

#define STAGE(BUF) { \
  cp16(kp0, smem + (BUF) * 8192 + fk); cp16(kp1, smem + (BUF) * 8192 + fk + 1024); \
  cp16(vp0, smem + (BUF) * 8192 + fv); cp16(vp1, smem + (BUF) * 8192 + fv + 1024); \
  kp0 += 2048; kp1 += 2048; vp0 += 32; vp1 += 32; \
}

#define TILEC(BUF, MWORD, SH) { \
  const unsigned char* kr = smem + (BUF) * 8192 + lb; \
  __builtin_amdgcn_s_setprio(1); \
  f32x16 s = mfma32(*(const bf16x8*)(kr), qf0, Z16); \
  s = mfma32(*(const bf16x8*)(kr + 1024), qf1, s); \
  s = mfma32(*(const bf16x8*)(kr + 2048), qf2, s); \
  s = mfma32(*(const bf16x8*)(kr + 3072), qf3, s); \
  __builtin_amdgcn_s_setprio(0); \
  const unsigned mwk = (MWORD) >> (SH); \
  float p[16]; \
  _Pragma("unroll") \
  for (int r = 0; r < 16; ++r) { \
    float e = __builtin_amdgcn_exp2f(s[r]); \
    unsigned kbit = (unsigned)(((int)(mwk << (31 - r))) >> 31); \
    e = __builtin_bit_cast(float, __builtin_bit_cast(unsigned, e) & kbit); \
    p[r] = e; \
    if ((r & 3) == 0) la0 += e; else if ((r & 3) == 1) la1 += e; \
    else if ((r & 3) == 2) la2 += e; else la3 += e; \
  } \
  bf16x8 bp0, bp1; \
  { unsigned Wa = pk2(p[0], p[1]), Wb = pk2(p[2], p[3]); \
    unsigned Wc = pk2(p[4], p[5]), Wd = pk2(p[6], p[7]); \
    uint2v s02 = __builtin_amdgcn_permlane32_swap(Wa, Wc, false, false); \
    uint2v s13 = __builtin_amdgcn_permlane32_swap(Wb, Wd, false, false); \
    uint4v fw; fw[0] = s02[0]; fw[1] = s13[0]; fw[2] = s02[1]; fw[3] = s13[1]; \
    bp0 = __builtin_bit_cast(bf16x8, fw); } \
  { unsigned Wa = pk2(p[8], p[9]), Wb = pk2(p[10], p[11]); \
    unsigned Wc = pk2(p[12], p[13]), Wd = pk2(p[14], p[15]); \
    uint2v s02 = __builtin_amdgcn_permlane32_swap(Wa, Wc, false, false); \
    uint2v s13 = __builtin_amdgcn_permlane32_swap(Wb, Wd, false, false); \
    uint4v fw; fw[0] = s02[0]; fw[1] = s13[0]; fw[2] = s02[1]; fw[3] = s13[1]; \
    bp1 = __builtin_bit_cast(bf16x8, fw); } \
  const unsigned char* vr = kr + 4096; \
  __builtin_amdgcn_s_setprio(1); \
  o0 = mfma32(*(const bf16x8*)(vr), bp0, o0); \
  o0 = mfma32(*(const bf16x8*)(vr + 1024), bp1, o0); \
  o1 = mfma32(*(const bf16x8*)(vr + 2048), bp0, o1); \
  o1 = mfma32(*(const bf16x8*)(vr + 3072), bp1, o1); \
  __builtin_amdgcn_s_setprio(0); \
}

// stage-retired barrier: tile in BUF is fully in LDS (own + partner stage)
#define SYNC_STAGED \
  asm volatile("s_waitcnt vmcnt(4)" ::: "memory"); \
  __builtin_amdgcn_sched_barrier(0); \
  __builtin_amdgcn_s_barrier(); \
  __builtin_amdgcn_sched_barrier(0);

// read-complete barrier: all waves done reading the buffer just computed
#define SYNC_READ_DONE \
  __builtin_amdgcn_sched_barrier(0); \
  __builtin_amdgcn_s_barrier(); \
  __builtin_amdgcn_sched_barrier(0);

  // mask word stream (tracked loads, 1 pair ahead)
  const unsigned* mp = MW + (size_t)lh * NTILES * SLEN + qrow;

  STAGE(0)                       // tile 0 -> buf0
  unsigned mwc = *mp;            // word for pair 0 (tracked)

  for (int t2 = 0; t2 < 64; ++t2) {
    STAGE(1)                     // tile 2*t2+1 -> buf1 (buf1 read-complete since prev iter)
    SYNC_STAGED                  // tile 2*t2 resident
    const unsigned mwn = mp[(t2 < 63) ? SLEN : 0];     // next pair's word (tracked)
    TILEC(0, mwc, 0)             // compute tile 2*t2
    SYNC_READ_DONE               // buf0 safe to overwrite

    STAGE(0)                     // tile 2*t2+2 -> buf0 (dummy at t2==63: lands in ws)
    SYNC_STAGED                  // tile 2*t2+1 resident
    TILEC(1, mwc, 16)            // compute tile 2*t2+1
    SYNC_READ_DONE               // buf1 safe to overwrite

    mwc = mwn; mp += SLEN;
  }
#undef STAGE
#undef TILEC
#undef SYNC_STAGED
#undef SYNC_READ_DONE

  // drain dummy stage, sync partner before LDS reuse
  asm volatile("s_waitcnt vmcnt(0)" ::: "memory");
  __builtin_amdgcn_s_barrier();

  // ---- wave-private epilogue: normalize, hi/lo split, transpose, write ----
  float plsum = (la0 + la1) + (la2 + la3);
  plsum += __shfl_xor(plsum, 32);
  const float inv = 1.f / plsum;
  #pragma unroll
  for (int r = 0; r < 16; ++r) { o0[r] *= inv; o1[r] *= inv; }

  bf16* T = (bf16*)(smem + w * 8192);   // [32 q][72 bf16] per wave
  const int qq = lane >> 1, hf = lane & 1;
  bf16* dsth = ctxh + ((size_t)bh * SLEN + q0w + qq) * 64 + hf * 32;
  bf16* dstl = ctxl + ((size_t)bh * SLEN + q0w + qq) * 64 + hf * 32;
  const bf16* sp = T + qq * 72 + hf * 32;

  // hi plane
  #pragma unroll
  for (int r = 0; r < 16; ++r) {
    const int dr = (r & 3) + 8 * (r >> 2) + lh4;
    T[l31 * 72 + dr]      = (bf16)o0[r];
    T[l31 * 72 + 32 + dr] = (bf16)o1[r];
  }
  #pragma unroll
  for (int u = 0; u < 4; ++u) *(uint4v*)(dsth + u * 8) = *(const uint4v*)(sp + u * 8);
  // lo plane
  #pragma unroll
  for (int r = 0; r < 16; ++r) {
    const int dr = (r & 3) + 8 * (r >> 2) + lh4;
    const float h0 = (float)(bf16)o0[r];
    const float h1 = (float)(bf16)o1[r];
    T[l31 * 72 + dr]      = (bf16)(o0[r] - h0);
    T[l31 * 72 + 32 + dr] = (bf16)(o1[r] - h1);
  }
  #pragma unroll
  for (int u = 0; u < 4; ++u) *(uint4v*)(dstl + u * 8) = *(const uint4v*)(sp + u * 8);
}

// ---------------- kernel 5: output projection (hi/lo split GEMM) ----------------
__global__ __launch_bounds__(256, 2) void out_proj(
    const bf16* __restrict__ CH, const bf16* __restrict__ CL,
    const bf16* __restrict__ WH, const bf16* __restrict__ WL,
    const float* __restrict__ bo, float* __restrict__ out)
{
  __shared__ __align__(16) bf16 Af[2][4][4][64][8];  // 32KB
  const int tid = threadIdx.x, w = tid >> 6, lane = tid & 63, l31 = lane & 31, lh = lane >> 5;
  const int mt = blockIdx.x >> 3, nt = blockIdx.x & 7;
  const int bs0 = mt * 128, n0 = nt * 64;
  const int b = bs0 >> 12, sbase = bs0 & 4095;

  f32x16 a0, a1;
  #pragma unroll
  for (int r = 0; r < 16; ++r) { a0[r] = 0.f; a1[r] = 0.f; }

  for (int kk = 0; kk < 8; ++kk) {
    __syncthreads();
    #pragma unroll
    for (int qq = 0; qq < 8; ++qq) {
      const int fid = w * 8 + qq, pl = fid >> 4, mb = (fid >> 2) & 3, c = fid & 3;
      const bf16* src = (pl ? CL : CH) +
          ((size_t)(b * 8 + kk) * SLEN + sbase + 32 * mb + l31) * 64 + 16 * c + 8 * lh;
      cp16(src, &Af[pl][mb][c][0][0]);
    }
    __syncthreads();

    bf16x8 bh0[4], bl0[4], bh1[4], bl1[4], ah[4], al[4];
    #pragma unroll
    for (int c = 0; c < 4; ++c) {
      const size_t o0off = (size_t)(n0 + l31) * EMB + kk * 64 + 16 * c + 8 * lh;
      const size_t o1off = (size_t)(n0 + l31 + 32) * EMB + kk * 64 + 16 * c + 8 * lh;
      bh0[c] = *(const bf16x8*)(WH + o0off);
      bl0[c] = *(const bf16x8*)(WL + o0off);
      bh1[c] = *(const bf16x8*)(WH + o1off);
      bl1[c] = *(const bf16x8*)(WL + o1off);
      ah[c] = *(const bf16x8*)(&Af[0][w][c][lane][0]);
      al[c] = *(const bf16x8*)(&Af[1][w][c][lane][0]);
    }
    #pragma unroll
    for (int c = 0; c < 4; ++c) {
      a0 = mfma32(ah[c], bh0[c], a0);
      a0 = mfma32(ah[c], bl0[c], a0);
      a0 = mfma32(al[c], bh0[c], a0);
      a1 = mfma32(ah[c], bh1[c], a1);
      a1 = mfma32(ah[c], bl1[c], a1);
      a1 = mfma32(al[c], bh1[c], a1);
    }
  }

  const float bv0 = bo[n0 + l31], bv1 = bo[n0 + l31 + 32];
  #pragma unroll
  for (int r = 0; r < 16; ++r) {
    const int row = bs0 + w * 32 + (r & 3) + 8 * (r >> 2) + 4 * lh;
    out[(size_t)row * EMB + n0 + l31]      = a0[r] + bv0;
    out[(size_t)row * EMB + n0 + l31 + 32] = a1[r] + bv1;
  }
}

// ---------------- launch ----------------
extern "C" void kernel_launch(void* const* d_in, const int* in_sizes, int n_in,
                              void* d_out, int out_size, void* d_ws, size_t ws_size,
                              hipStream_t stream)
{
  (void)in_sizes; (void)n_in; (void)out_size; (void)ws_size;
  const float* key   = (const float*)d_in[0];
  const float* query = (const float*)d_in[1];
  const float* value = (const float*)d_in[2];
  const int*   mask  = (const int*)d_in[3];
  const float* Wq    = (const float*)d_in[4];
  const float* Wk    = (const float*)d_in[5];
  const float* Wv    = (const float*)d_in[6];
  const float* Wo    = (const float*)d_in[7];
  const float* bo    = (const float*)d_in[8];
  float* out = (float*)d_out;

  char* ws = (char*)d_ws;                       // ~43.5 MB used
  bf16* Qb = (bf16*)(ws);                       // 8 MB  [BH][S][64] (pre-scaled)
  bf16* Kb = (bf16*)(ws + (8ull  << 20));       // 8 MB  [BH][S][64]
  bf16* VT = (bf16*)(ws + (16ull << 20));       // 8 MB  [BH][64][S]
  unsigned* MW = (unsigned*)(ws + (24ull << 20));  // 2 MB [lh][tile64][q]
  bf16* CH = (bf16*)(ws + (26ull << 20));       // 8 MB  ctx hi
  bf16* CL = (bf16*)(ws + (34ull << 20));       // 8 MB  ctx lo
  bf16* WH = (bf16*)(ws + (42ull << 20));       // 512 KB
  bf16* WL = (bf16*)(ws + (42ull << 20) + (512ull << 10));

  proj_qkv<<<512, 256, 0, stream>>>(key, query, value, Wq, Wk, Wv, Qb, Kb, VT);
  pack_mask<<<1024, 256, 0, stream>>>(mask, MW);
  wo_split<<<256, 256, 0, stream>>>(Wo, WH, WL);
  attn_kernel<<<1024, 128, 0, stream>>>(Qb, Kb, VT, MW, CH, CL);
  out_proj<<<512, 256, 0, stream>>>(CH, CL, WH, WL, bo, out);
}